// Round 1
// baseline (258.071 us; speedup 1.0000x reference)
//
#include <hip/hip_runtime.h>
#include <math.h>

// EdgeAwareLoss: canny-style edge weight on target, weighted BCE mean.
//
// Math notes (why this is exact vs the JAX reference):
//  - img = (target>0.5)*255 with integer Sobel weights => m = |gx|+|gy| is a
//    multiple of 255. Hence (m>50) == (m>150) == (m>=255): weak set == strong
//    set, and the hysteresis while_loop is a fixed point immediately
//    (ns = max(s, min(s, dilate(s))) = s). Final strong == cand. No iteration.
//  - All gradient math done in units of 255: gx,gy in [-4,4], m in [0,8].
//  - NMS uses zero-padded m, but interior mask excludes border pixels, so all
//    sampled neighbor m-values are in-image; conv 'edge' pad == coordinate clamp.
//  - target is exactly {0.0,1.0}; binarized LDS value == t for the BCE term.

#define TS 64        // output tile
#define IR 72        // img region: tile +/-4 (strong needs m +/-1, m needs img +/-1, edge_zone +/-2)
#define MR 70        // m/gradient region: tile +/-3
#define SR 68        // strong region: tile +/-2
#define NTHREADS 256

__global__ __launch_bounds__(NTHREADS)
void edge_loss_kernel(const float* __restrict__ pred,
                      const float* __restrict__ target,
                      double* __restrict__ acc,
                      int H, int W)
{
    __shared__ unsigned char simg[IR][IR + 1];  // binarized target (also == t)
    __shared__ unsigned char sg[MR][MR + 1];    // packed (gx+4) | ((gy+4)<<4)
    __shared__ unsigned char sm[MR][MR + 1];    // m = |gx|+|gy| in units of 255
    __shared__ unsigned char ss[SR][SR + 1];    // strong (== final hysteresis result)
    __shared__ unsigned char sh[SR][TS + 1];    // horizontal 5-wide OR of strong
    __shared__ float wsum[NTHREADS / 64];

    const int tid = threadIdx.x;
    const int b  = blockIdx.z;
    const int r0 = blockIdx.y * TS;
    const int c0 = blockIdx.x * TS;
    const float* timg = target + (size_t)b * H * W;
    const float* pimg = pred   + (size_t)b * H * W;

    // Stage 0: load binarized target with edge-replicate clamp (== conv 'edge' pad)
    for (int idx = tid; idx < IR * IR; idx += NTHREADS) {
        int i = idx / IR, j = idx % IR;
        int r = r0 - 4 + i; r = r < 0 ? 0 : (r > H - 1 ? H - 1 : r);
        int c = c0 - 4 + j; c = c < 0 ? 0 : (c > W - 1 ? W - 1 : c);
        simg[i][j] = (timg[(size_t)r * W + c] > 0.5f) ? 1 : 0;
    }
    __syncthreads();

    // Stage A: Sobel gradients over m-region (units of 255)
    for (int idx = tid; idx < MR * MR; idx += NTHREADS) {
        int i = idx / MR, j = idx % MR;           // m-region [i][j] <-> img [i+1][j+1]
        int a  = simg[i][j],     bb = simg[i][j + 1],     cc = simg[i][j + 2];
        int d  = simg[i + 1][j],                          f  = simg[i + 1][j + 2];
        int g  = simg[i + 2][j], h  = simg[i + 2][j + 1], ii = simg[i + 2][j + 2];
        int gx = (cc - a) + 2 * (f - d) + (ii - g);
        int gy = (g - a) + 2 * (h - bb) + (ii - cc);
        int ax = gx < 0 ? -gx : gx;
        int ay = gy < 0 ? -gy : gy;
        sm[i][j] = (unsigned char)(ax + ay);
        sg[i][j] = (unsigned char)((gx + 4) | ((gy + 4) << 4));
    }
    __syncthreads();

    // Stage B: NMS + threshold -> strong
    for (int idx = tid; idx < SR * SR; idx += NTHREADS) {
        int i = idx / SR, j = idx % SR;           // s-region [i][j] <-> m-region [i+1][j+1]
        int gp = sg[i + 1][j + 1];
        int gx = (gp & 15) - 4, gy = (gp >> 4) - 4;
        int ax = gx < 0 ? -gx : gx;
        int ay = gy < 0 ? -gy : gy;
        int m = ax + ay;
        float fax = (float)ax, fay = (float)ay;
        bool horiz = fay < fax * 0.41421356237f;   // TG22
        bool vert  = fay > fax * 2.41421356237f;   // TG67
        bool sd    = (gx * gy) < 0;
        // n1 per direction; n2 = -n1.  keep = (m > m[n1]) & (m >= m[n2])
        int dr1 = horiz ? 0  : -1;
        int dc1 = horiz ? -1 : (vert ? 0 : (sd ? 1 : -1));
        int m1 = sm[i + 1 + dr1][j + 1 + dc1];
        int m2 = sm[i + 1 - dr1][j + 1 - dc1];
        int r = r0 - 2 + i, c = c0 - 2 + j;
        bool interior = (r >= 1) && (r <= H - 2) && (c >= 1) && (c <= W - 2);
        bool strong = interior && (m > m1) && (m >= m2) && (m >= 1);
        ss[i][j] = strong ? 1 : 0;
    }
    __syncthreads();

    // Stage C: horizontal 5-wide OR (separable 5x5 dilation, zero-padded by interior mask)
    for (int idx = tid; idx < SR * TS; idx += NTHREADS) {
        int i = idx / TS, j = idx % TS;           // s-row i, tile col j (s-col j+2)
        sh[i][j] = (unsigned char)(ss[i][j] | ss[i][j + 1] | ss[i][j + 2] |
                                   ss[i][j + 3] | ss[i][j + 4]);
    }
    __syncthreads();

    // Stage D: vertical 5-OR -> edge zone; weighted BCE; accumulate
    float accv = 0.0f;
    for (int idx = tid; idx < TS * TS; idx += NTHREADS) {
        int i = idx / TS, j = idx % TS;
        unsigned char ez = (unsigned char)(sh[i][j] | sh[i + 1][j] | sh[i + 2][j] |
                                           sh[i + 3][j] | sh[i + 4][j]);
        float w = ez ? 5.0f : 1.0f;
        float t = (float)simg[i + 4][j + 4];
        float p = pimg[(size_t)(r0 + i) * W + (c0 + j)];
        float lp  = fmaxf(logf(p), -100.0f);
        float l1p = fmaxf(log1pf(-p), -100.0f);
        float bce = -(t * lp + (1.0f - t) * l1p);
        accv += bce * w;
    }

    // Block reduction: wave shuffle then cross-wave via LDS
    for (int off = 32; off > 0; off >>= 1)
        accv += __shfl_down(accv, off);
    int wid = tid >> 6, lane = tid & 63;
    if (lane == 0) wsum[wid] = accv;
    __syncthreads();
    if (tid == 0) {
        float s = wsum[0] + wsum[1] + wsum[2] + wsum[3];
        atomicAdd(acc, (double)s);
    }
}

__global__ void finalize_kernel(const double* __restrict__ acc,
                                float* __restrict__ out, double invN)
{
    out[0] = (float)(acc[0] * invN);
}

extern "C" void kernel_launch(void* const* d_in, const int* in_sizes, int n_in,
                              void* d_out, int out_size, void* d_ws, size_t ws_size,
                              hipStream_t stream)
{
    (void)n_in; (void)out_size; (void)ws_size;
    const float* pred   = (const float*)d_in[0];
    const float* target = (const float*)d_in[1];
    const int H = 1024, W = 1024;
    const int N = in_sizes[0];
    const int B = N / (H * W);

    double* acc = (double*)d_ws;
    hipMemsetAsync(d_ws, 0, sizeof(double), stream);

    dim3 grid(W / TS, H / TS, B);
    edge_loss_kernel<<<grid, NTHREADS, 0, stream>>>(pred, target, acc, H, W);
    finalize_kernel<<<1, 1, 0, stream>>>(acc, (float*)d_out, 1.0 / (double)N);
}

// Round 2
// 163.651 us; speedup vs baseline: 1.5770x; 1.5770x over previous
//
#include <hip/hip_runtime.h>
#include <math.h>

// EdgeAwareLoss — nibble-SWAR bit-parallel rewrite.
//
// Exactness arguments vs the JAX reference:
//  - img = (t>0.5)*255, integer Sobel => m is a multiple of 255, so
//    (m>50)==(m>150): weak==strong, hysteresis loop is an immediate fixed
//    point => strong == cand (validated: round-1 absmax 0.0).
//  - In units of 255: gx,gy in [-4,4], and |gx|+|gy| = max(|gx+gy|,|gx-gy|)
//    <= 6, so m fits a nibble and SWAR compares ((x|8)-y)&8 are exact (<=7).
//  - Direction classes enumerated exactly over the integer grid:
//      horiz (ay < ax*tan22.5): ay==0&&ax>=1 || ay==1&&ax>=3
//      vert  (ay > ax*tan67.5): ax==0&&ay>=1 || ax==1&&ay>=3
//  - t is exactly {0,1} => bce = -max(log(t?p:1-p), -100); 1-p is exact for
//    p>=0.5 (Sterbenz) and >=0.5 otherwise => ~1ulp, threshold 0.099.
//
// Tile 64x64. Regions: img 72x72 (nibble-packed, 12 uints/row, cols>=72 zero),
// m/classes 70 rows x 6 u64 words (16 nibbles each; word5 zero),
// strong 68 rows x 5 u16 bitmasks, h/ez row bitmasks (u64).

typedef unsigned long long u64;
typedef unsigned int u32;
typedef unsigned short u16;

#define NT 256
#define H_IMG 1024
#define W_IMG 1024

constexpr u64 K1 = 0x1111111111111111ULL;
constexpr u64 K7 = 0x7777777777777777ULL;
constexpr u64 K8 = 0x8888888888888888ULL;

// per-nibble x >= y (values <= 7): result mask in bit3 of each nibble
__device__ __forceinline__ u64 geq8(u64 x, u64 y) { return ((x | K8) - y) & K8; }
// per-nibble x > y  == !(y >= x)
__device__ __forceinline__ u64 gt8(u64 x, u64 y) { return K8 & ~((y | K8) - x); }

__global__ __launch_bounds__(NT)
void edge_loss_kernel(const float* __restrict__ pred,
                      const float* __restrict__ target,
                      float* __restrict__ partials)
{
    __shared__ u32 simg[72][12];   // nibble-packed binarized target
    __shared__ u64 mw[70][6];      // m (nibbles, <=6)
    __shared__ u64 hzw[70][6];     // horiz class (bit0/nibble)
    __shared__ u64 vtw[70][6];     // vert class
    __shared__ u64 sdw[70][6];     // sign-diff class
    __shared__ u16 ssw[68][5];     // strong, 16 px bitmasks
    __shared__ u64 hrow[68];       // horizontal 5-OR row masks
    __shared__ u64 ezrow[64];      // edge-zone row masks (tile cols)
    __shared__ float wsum[NT / 64];

    const int tid = threadIdx.x;
    const int bz = blockIdx.z;
    const int r0 = blockIdx.y * 64;
    const int c0 = blockIdx.x * 64;
    const float* timg = target + (size_t)bz * H_IMG * W_IMG;
    const float* pimg = pred   + (size_t)bz * H_IMG * W_IMG;

    // ---- Stage 0: load+binarize+nibble-pack target (8 px per u32) ----
    for (int t = tid; t < 72 * 12; t += NT) {
        int irow = t / 12, wu = t - irow * 12;
        u32 v = 0;
        if (wu < 9) {
            int r = r0 - 4 + irow; r = r < 0 ? 0 : (r > H_IMG - 1 ? H_IMG - 1 : r);
            const float* trp = timg + (size_t)r * W_IMG;
            int cbase = c0 - 4 + wu * 8;
#pragma unroll
            for (int k = 0; k < 8; ++k) {
                int c = cbase + k; c = c < 0 ? 0 : (c > W_IMG - 1 ? W_IMG - 1 : c);
                v |= (trp[c] > 0.5f ? 1u : 0u) << (4 * k);
            }
        }
        simg[irow][wu] = v;
    }
    __syncthreads();

    // ---- Stage A: SWAR Sobel -> m + direction classes (16 px / task) ----
    for (int t = tid; t < 70 * 6; t += NT) {
        int mrow = t / 6, wi = t - mrow * 6;
        if (wi == 5) {  // zero pad word (read as wi+1 in stage B)
            mw[mrow][5] = 0; hzw[mrow][5] = 0; vtw[mrow][5] = 0; sdw[mrow][5] = 0;
            continue;
        }
        u64 Lr[3], Cr[3], Rr[3];
#pragma unroll
        for (int k = 0; k < 3; ++k) {
            int ir = mrow + k;
            u32 a0 = simg[ir][2 * wi], a1 = simg[ir][2 * wi + 1], a2 = simg[ir][2 * wi + 2];
            u64 w0 = (u64)a0 | ((u64)a1 << 32);
            Lr[k] = w0;                                        // col-1 of center
            Cr[k] = (w0 >> 4) | ((u64)(a2 & 0xFu) << 60);      // center col
            Rr[k] = (w0 >> 8) | ((u64)(a2 & 0xFFu) << 56);     // col+1
        }
        u64 Px = Rr[0] + (Rr[1] << 1) + Rr[2];   // c + 2f + i   (<=4/nibble)
        u64 Nx = Lr[0] + (Lr[1] << 1) + Lr[2];   // a + 2d + g
        u64 Py = Lr[2] + (Cr[2] << 1) + Rr[2];   // g + 2h + i
        u64 Ny = Lr[0] + (Cr[0] << 1) + Rr[0];   // a + 2b + c
        u64 Dbx = (Px + K8) - Nx;                // gx+8 in [4,12], no borrows
        u64 Dby = (Py + K8) - Ny;

        u64 mx = (Dbx >> 3) & K1;                // gx >= 0
        u64 mfx = (mx << 4) - mx;                // 0xF per positive lane
        u64 ax = ((Dbx & K7) & mfx) | (((((~Dbx) & K7) + K1)) & ~mfx);
        u64 my = (Dby >> 3) & K1;
        u64 mfy = (my << 4) - my;
        u64 ay = ((Dby & K7) & mfy) | (((((~Dby) & K7) + K1)) & ~mfy);
        u64 m = ax + ay;                         // <= 6

        u64 ax0 = ax & K1, ax1b = (ax >> 1) & K1, ax2b = (ax >> 2) & K1;
        u64 ay0 = ay & K1, ay1b = (ay >> 1) & K1, ay2b = (ay >> 2) & K1;
        u64 axnz = ax0 | ax1b | ax2b;
        u64 aynz = ay0 | ay1b | ay2b;
        u64 axe1 = ax0 & ~(ax1b | ax2b);
        u64 aye1 = ay0 & ~(ay1b | ay2b);
        u64 axg3 = ax2b | (ax1b & ax0);
        u64 ayg3 = ay2b | (ay1b & ay0);
        u64 horiz = ((K1 & ~aynz) & axnz) | (aye1 & axg3);
        u64 vert  = ((K1 & ~axnz) & aynz) | (axe1 & ayg3);

        u64 gxp = mx & ((Dbx | (Dbx >> 1) | (Dbx >> 2)) & K1);  // gx > 0
        u64 gxn = K1 & ~mx;                                     // gx < 0
        u64 gyp = my & ((Dby | (Dby >> 1) | (Dby >> 2)) & K1);
        u64 gyn = K1 & ~my;
        u64 sd = (gxp & gyn) | (gxn & gyp);

        mw[mrow][wi] = m;
        hzw[mrow][wi] = horiz;
        vtw[mrow][wi] = vert;
        sdw[mrow][wi] = sd;
    }
    __syncthreads();

    // ---- Stage B: SWAR NMS + threshold + interior -> strong bitmasks ----
    for (int t = tid; t < 68 * 5; t += NT) {
        int srow = t / 5, wi = t - srow * 5;
        u16 outm = 0;
        int rr = r0 - 2 + srow;
        if (rr >= 1 && rr <= H_IMG - 2) {
            int ra = srow, rb = srow + 1, rc = srow + 2;
            u64 a0 = mw[ra][wi], a1 = mw[ra][wi + 1];
            u64 b0 = mw[rb][wi], b1 = mw[rb][wi + 1];
            u64 g0 = mw[rc][wi], g1 = mw[rc][wi + 1];
            u64 U  = (a0 >> 4) | (a1 << 60);
            u64 UL = a0;
            u64 UR = (a0 >> 8) | (a1 << 56);
            u64 M  = (b0 >> 4) | (b1 << 60);
            u64 Lf = b0;
            u64 Rg = (b0 >> 8) | (b1 << 56);
            u64 Dn = (g0 >> 4) | (g1 << 60);
            u64 DL = g0;
            u64 DR = (g0 >> 8) | (g1 << 56);

            u64 h0 = hzw[rb][wi], h1 = hzw[rb][wi + 1];
            u64 v0 = vtw[rb][wi], v1 = vtw[rb][wi + 1];
            u64 s0 = sdw[rb][wi], s1 = sdw[rb][wi + 1];
            u64 H8 = ((h0 >> 4) | (h1 << 60)) << 3;
            u64 V8 = ((v0 >> 4) | (v1 << 60)) << 3;
            u64 S8 = ((s0 >> 4) | (s1 << 60)) << 3;

            u64 kH = gt8(M, Lf) & geq8(M, Rg);
            u64 kV = gt8(M, U)  & geq8(M, Dn);
            u64 kA = gt8(M, UR) & geq8(M, DL);   // sign_diff branch
            u64 kB = gt8(M, UL) & geq8(M, DR);
            u64 nHV = K8 & ~(H8 | V8);
            u64 keep = (H8 & kH) | (V8 & kV) | (nHV & S8 & kA) | (nHV & ~S8 & kB);
            u64 nz = ((M | (M >> 1) | (M >> 2)) & K1) << 3;   // m >= 1
            u64 cand = keep & nz;

            int basec = c0 - 2 + 16 * wi;          // global col of lane 0
            int lo = 1 - basec; if (lo < 0) lo = 0;
            int hi = (W_IMG - 2) - basec; if (hi > 15) hi = 15;
            if (lo > hi) cand = 0;
            else cand &= (~0ULL >> ((15 - hi) * 4)) & (~0ULL << (lo * 4));

            u64 x = cand >> 3;                      // bits at 4k
            x = (x | (x >> 3))  & 0x0303030303030303ULL;
            x = (x | (x >> 6))  & 0x000F000F000F000FULL;
            x = (x | (x >> 12)) & 0x000000FF000000FFULL;
            x = (x | (x >> 24));
            outm = (u16)(x & 0xFFFF);
        }
        ssw[srow][wi] = outm;
    }
    __syncthreads();

    // ---- Stage C1: horizontal 5-OR over strong row bitmasks ----
    for (int t = tid; t < 68; t += NT) {
        u64 lo = (u64)ssw[t][0] | ((u64)ssw[t][1] << 16) |
                 ((u64)ssw[t][2] << 32) | ((u64)ssw[t][3] << 48);
        u64 hib = (u64)(ssw[t][4] & 0xFu);          // s-cols 64..67 only
        u64 acc = lo;
#pragma unroll
        for (int d = 1; d <= 4; ++d)
            acc |= (lo >> d) | (hib << (64 - d));
        hrow[t] = acc;
    }
    __syncthreads();

    // ---- Stage C2: vertical 5-OR -> edge zone per tile row ----
    for (int t = tid; t < 64; t += NT)
        ezrow[t] = hrow[t] | hrow[t + 1] | hrow[t + 2] | hrow[t + 3] | hrow[t + 4];
    __syncthreads();

    // ---- Stage D: weighted BCE; 16 px per thread, float4 pred loads ----
    float accv = 0.0f;
    {
        int trow = tid >> 2;
        int tcb = (tid & 3) * 16;
        u64 ezw = ezrow[trow] >> tcb;
        int q = (tcb + 4) >> 3;                    // nibble offset 4 within u32 q
        u32 ua = simg[trow + 4][q], ub = simg[trow + 4][q + 1], uc = simg[trow + 4][q + 2];
        u64 tb = ((u64)(ua >> 16)) | ((u64)ub << 16) | (((u64)(uc & 0xFFFFu)) << 48);
        const float4* pv4 = (const float4*)(pimg + (size_t)(r0 + trow) * W_IMG + (c0 + tcb));
#pragma unroll
        for (int kk = 0; kk < 4; ++kk) {
            float4 pv = pv4[kk];
            float ps[4] = {pv.x, pv.y, pv.z, pv.w};
#pragma unroll
            for (int cc = 0; cc < 4; ++cc) {
                int k = kk * 4 + cc;
                float p = ps[cc];
                float xx = ((tb >> (4 * k)) & 1) ? p : 1.0f - p;
                float lg = fmaxf(__logf(xx), -100.0f);
                float w = ((ezw >> k) & 1) ? 5.0f : 1.0f;
                accv = fmaf(w, -lg, accv);
            }
        }
    }

    // block reduction -> per-block partial (no global atomics, no memset dep)
    for (int off = 32; off > 0; off >>= 1)
        accv += __shfl_down(accv, off);
    int wid = tid >> 6, lane = tid & 63;
    if (lane == 0) wsum[wid] = accv;
    __syncthreads();
    if (tid == 0) {
        int bi = (blockIdx.z * gridDim.y + blockIdx.y) * gridDim.x + blockIdx.x;
        partials[bi] = wsum[0] + wsum[1] + wsum[2] + wsum[3];
    }
}

__global__ __launch_bounds__(256)
void finalize_kernel(const float* __restrict__ partials, float* __restrict__ out,
                     int nblocks, double invN)
{
    __shared__ double ws[4];
    double s = 0.0;
    for (int i = threadIdx.x; i < nblocks; i += 256) s += (double)partials[i];
    for (int off = 32; off > 0; off >>= 1) s += __shfl_down(s, off);
    int wid = threadIdx.x >> 6, lane = threadIdx.x & 63;
    if (lane == 0) ws[wid] = s;
    __syncthreads();
    if (threadIdx.x == 0) out[0] = (float)((ws[0] + ws[1] + ws[2] + ws[3]) * invN);
}

extern "C" void kernel_launch(void* const* d_in, const int* in_sizes, int n_in,
                              void* d_out, int out_size, void* d_ws, size_t ws_size,
                              hipStream_t stream)
{
    (void)n_in; (void)out_size; (void)ws_size;
    const float* pred   = (const float*)d_in[0];
    const float* target = (const float*)d_in[1];
    const int N = in_sizes[0];
    const int B = N / (H_IMG * W_IMG);

    float* partials = (float*)d_ws;   // fully overwritten every call
    dim3 grid(W_IMG / 64, H_IMG / 64, B);
    int nblocks = (W_IMG / 64) * (H_IMG / 64) * B;

    edge_loss_kernel<<<grid, NT, 0, stream>>>(pred, target, partials);
    finalize_kernel<<<1, 256, 0, stream>>>(partials, (float*)d_out, nblocks,
                                           1.0 / (double)N);
}

// Round 3
// 151.420 us; speedup vs baseline: 1.7043x; 1.0808x over previous
//
#include <hip/hip_runtime.h>
#include <math.h>

// EdgeAwareLoss — nibble-SWAR, round 3.
//
// Exactness arguments vs the JAX reference (validated absmax 0.0 in r1/r2):
//  - img = (t>0.5)*255, integer Sobel => m is a multiple of 255, so
//    (m>50)==(m>150): weak==strong, hysteresis loop is an immediate fixed
//    point => strong == cand. No iteration.
//  - In units of 255: gx,gy in [-4,4], |gx|+|gy| <= 6, so m fits a nibble and
//    SWAR compares ((x|8)-y)&8 are exact (values <= 7).
//  - Direction classes enumerated exactly over the integer grid:
//      horiz (ay < ax*tan22.5): ay==0&&ax>=1 || ay==1&&ax>=3
//      vert  (ay > ax*tan67.5): ax==0&&ay>=1 || ax==1&&ay>=3
//  - t in {0,1} => bce = -max(log(t?p:1-p), -100); 1-p exact for p>=0.5
//    (Sterbenz) and >=0.5 otherwise.
//
// Round-3 changes (r2 was 59.5us, VALUBusy 44%, HBM 21% — latency/VALU fat):
//  - binarize pre-pass: target -> 1 bit/px packed in d_ws (coalesced float4
//    reads); main-kernel stage 0 = 4 cached u32 loads + bit->nibble spreads,
//    replacing 5184 strided scalar loads + clamps per block.
//  - horiz/vert/sd consolidated into ONE nibble-plane array (bits 0/1/2).
//  - stage C2 folded into stage D (one fewer barrier).

typedef unsigned long long u64;
typedef unsigned int u32;
typedef unsigned short u16;

#define NT 256
#define H_IMG 1024
#define W_IMG 1024
#define WPR 32                 // packed u32 words per image row

constexpr u64 K1 = 0x1111111111111111ULL;
constexpr u64 K7 = 0x7777777777777777ULL;
constexpr u64 K8 = 0x8888888888888888ULL;

__device__ __forceinline__ u64 geq8(u64 x, u64 y) { return ((x | K8) - y) & K8; }
__device__ __forceinline__ u64 gt8(u64 x, u64 y) { return K8 & ~((y | K8) - x); }

// ---- pre-pass: binarize target to 1 bit/px ----
__global__ __launch_bounds__(256)
void binarize_kernel(const float* __restrict__ target, u32* __restrict__ packed,
                     int nwords)
{
    int t = blockIdx.x * 256 + threadIdx.x;
    if (t >= nwords) return;
    const float4* src = (const float4*)target + (size_t)t * 8;
    u32 v = 0;
#pragma unroll
    for (int k = 0; k < 8; ++k) {
        float4 f = src[k];
        v |= (f.x > 0.5f ? 1u : 0u) << (4 * k);
        v |= (f.y > 0.5f ? 2u : 0u) << (4 * k);
        v |= (f.z > 0.5f ? 4u : 0u) << (4 * k);
        v |= (f.w > 0.5f ? 8u : 0u) << (4 * k);
    }
    packed[t] = v;
}

__global__ __launch_bounds__(NT)
void edge_loss_kernel(const float* __restrict__ pred,
                      const u32* __restrict__ packed,
                      float* __restrict__ partials)
{
    __shared__ u32 simg[72][11];   // nibble-packed binarized target (q<=10)
    __shared__ u64 mw[70][6];      // m (nibbles, <=6); word5 zero
    __shared__ u64 clw[70][6];     // class nibbles: bit0=horiz bit1=vert bit2=sd
    __shared__ u16 ssw[68][5];     // strong, 16 px bitmasks
    __shared__ u64 hrow[68];       // horizontal 5-OR row masks
    __shared__ float wsum[NT / 64];

    const int tid = threadIdx.x;
    const int bz = blockIdx.z;
    const int r0 = blockIdx.y * 64;
    const int c0 = blockIdx.x * 64;
    const float* pimg = pred + (size_t)bz * H_IMG * W_IMG;
    const u32* pb = packed + (size_t)bz * H_IMG * WPR;
    const int W0 = c0 >> 5;        // even; c0 multiple of 64

    // ---- Stage 0: packed bits -> nibble LDS, with edge-replicate clamp ----
    for (int t = tid; t < 72; t += NT) {
        int r = r0 - 4 + t; r = r < 0 ? 0 : (r > H_IMG - 1 ? H_IMG - 1 : r);
        const u32* prow = pb + r * WPR;
        u32 Bw = prow[W0];
        u32 Cw = prow[W0 + 1];
        u32 Aw = (W0 > 0) ? prow[W0 - 1] : ((Bw & 1u) ? ~0u : 0u);
        u32 Dw = (W0 + 2 < WPR) ? prow[W0 + 2] : ((Cw >> 31) ? ~0u : 0u);
        // 72-bit window, bit j = img col c0-4+j
        u64 lo = (u64)(Aw >> 28) | ((u64)Bw << 4) | ((u64)Cw << 36);
        u32 hi = (Cw >> 28) | ((Dw & 0xFu) << 4);
#pragma unroll
        for (int q = 0; q < 9; ++q) {
            u32 x = (q < 8) ? (u32)((lo >> (8 * q)) & 0xFFu) : (hi & 0xFFu);
            x = (x | (x << 12)) & 0x000F000Fu;   // spread 8 bits -> 8 nibbles
            x = (x | (x << 6))  & 0x03030303u;
            x = (x | (x << 3))  & 0x11111111u;
            simg[t][q] = x;
        }
        simg[t][9] = 0; simg[t][10] = 0;
    }
    __syncthreads();

    // ---- Stage A: SWAR Sobel -> m + class planes (16 px / task) ----
    for (int t = tid; t < 70 * 6; t += NT) {
        int mrow = t / 6, wi = t - mrow * 6;
        if (wi == 5) { mw[mrow][5] = 0; clw[mrow][5] = 0; continue; }
        u64 Lr[3], Cr[3], Rr[3];
#pragma unroll
        for (int k = 0; k < 3; ++k) {
            int ir = mrow + k;
            u32 a0 = simg[ir][2 * wi], a1 = simg[ir][2 * wi + 1], a2 = simg[ir][2 * wi + 2];
            u64 w0 = (u64)a0 | ((u64)a1 << 32);
            Lr[k] = w0;                                        // col-1
            Cr[k] = (w0 >> 4) | ((u64)(a2 & 0xFu) << 60);      // center
            Rr[k] = (w0 >> 8) | ((u64)(a2 & 0xFFu) << 56);     // col+1
        }
        u64 Px = Rr[0] + (Rr[1] << 1) + Rr[2];
        u64 Nx = Lr[0] + (Lr[1] << 1) + Lr[2];
        u64 Py = Lr[2] + (Cr[2] << 1) + Rr[2];
        u64 Ny = Lr[0] + (Cr[0] << 1) + Rr[0];
        u64 Dbx = (Px + K8) - Nx;                // gx+8 per nibble, no borrows
        u64 Dby = (Py + K8) - Ny;

        u64 mx = (Dbx >> 3) & K1;                // gx >= 0
        u64 mfx = (mx << 4) - mx;
        u64 ax = ((Dbx & K7) & mfx) | (((((~Dbx) & K7) + K1)) & ~mfx);
        u64 my = (Dby >> 3) & K1;
        u64 mfy = (my << 4) - my;
        u64 ay = ((Dby & K7) & mfy) | (((((~Dby) & K7) + K1)) & ~mfy);
        u64 m = ax + ay;                         // <= 6

        u64 ax0 = ax & K1, ax1b = (ax >> 1) & K1, ax2b = (ax >> 2) & K1;
        u64 ay0 = ay & K1, ay1b = (ay >> 1) & K1, ay2b = (ay >> 2) & K1;
        u64 axnz = ax0 | ax1b | ax2b;
        u64 aynz = ay0 | ay1b | ay2b;
        u64 axe1 = ax0 & ~(ax1b | ax2b);
        u64 aye1 = ay0 & ~(ay1b | ay2b);
        u64 axg3 = ax2b | (ax1b & ax0);
        u64 ayg3 = ay2b | (ay1b & ay0);
        u64 horiz = ((K1 & ~aynz) & axnz) | (aye1 & axg3);
        u64 vert  = ((K1 & ~axnz) & aynz) | (axe1 & ayg3);

        u64 gxp = mx & ((Dbx | (Dbx >> 1) | (Dbx >> 2)) & K1);
        u64 gxn = K1 & ~mx;
        u64 gyp = my & ((Dby | (Dby >> 1) | (Dby >> 2)) & K1);
        u64 gyn = K1 & ~my;
        u64 sd = (gxp & gyn) | (gxn & gyp);

        mw[mrow][wi] = m;
        clw[mrow][wi] = horiz | (vert << 1) | (sd << 2);
    }
    __syncthreads();

    // ---- Stage B: SWAR NMS + threshold + interior -> strong bitmasks ----
    for (int t = tid; t < 68 * 5; t += NT) {
        int srow = t / 5, wi = t - srow * 5;
        u16 outm = 0;
        int rr = r0 - 2 + srow;
        if (rr >= 1 && rr <= H_IMG - 2) {
            int ra = srow, rb = srow + 1, rc = srow + 2;
            u64 a0 = mw[ra][wi], a1 = mw[ra][wi + 1];
            u64 b0 = mw[rb][wi], b1 = mw[rb][wi + 1];
            u64 g0 = mw[rc][wi], g1 = mw[rc][wi + 1];
            u64 U  = (a0 >> 4) | (a1 << 60);
            u64 UL = a0;
            u64 UR = (a0 >> 8) | (a1 << 56);
            u64 M  = (b0 >> 4) | (b1 << 60);
            u64 Lf = b0;
            u64 Rg = (b0 >> 8) | (b1 << 56);
            u64 Dn = (g0 >> 4) | (g1 << 60);
            u64 DL = g0;
            u64 DR = (g0 >> 8) | (g1 << 56);

            u64 q0 = clw[rb][wi], q1 = clw[rb][wi + 1];
            u64 CC = (q0 >> 4) | (q1 << 60);
            u64 H8 = (CC & K1) << 3;
            u64 V8 = ((CC >> 1) & K1) << 3;
            u64 S8 = ((CC >> 2) & K1) << 3;

            u64 kH = gt8(M, Lf) & geq8(M, Rg);
            u64 kV = gt8(M, U)  & geq8(M, Dn);
            u64 kA = gt8(M, UR) & geq8(M, DL);
            u64 kB = gt8(M, UL) & geq8(M, DR);
            u64 nHV = K8 & ~(H8 | V8);
            u64 keep = (H8 & kH) | (V8 & kV) | (nHV & S8 & kA) | (nHV & ~S8 & kB);
            u64 nz = ((M | (M >> 1) | (M >> 2)) & K1) << 3;   // m >= 1
            u64 cand = keep & nz;

            int basec = c0 - 2 + 16 * wi;
            int lo = 1 - basec; if (lo < 0) lo = 0;
            int hi = (W_IMG - 2) - basec; if (hi > 15) hi = 15;
            if (lo > hi) cand = 0;
            else cand &= (~0ULL >> ((15 - hi) * 4)) & (~0ULL << (lo * 4));

            u64 x = cand >> 3;
            x = (x | (x >> 3))  & 0x0303030303030303ULL;
            x = (x | (x >> 6))  & 0x000F000F000F000FULL;
            x = (x | (x >> 12)) & 0x000000FF000000FFULL;
            x = (x | (x >> 24));
            outm = (u16)(x & 0xFFFF);
        }
        ssw[srow][wi] = outm;
    }
    __syncthreads();

    // ---- Stage C: horizontal 5-OR over strong row bitmasks ----
    for (int t = tid; t < 68; t += NT) {
        u64 lo = (u64)ssw[t][0] | ((u64)ssw[t][1] << 16) |
                 ((u64)ssw[t][2] << 32) | ((u64)ssw[t][3] << 48);
        u64 hib = (u64)(ssw[t][4] & 0xFu);
        u64 acc = lo;
#pragma unroll
        for (int d = 1; d <= 4; ++d)
            acc |= (lo >> d) | (hib << (64 - d));
        hrow[t] = acc;
    }
    __syncthreads();

    // ---- Stage D: vertical 5-OR + weighted BCE; 16 px / thread ----
    float accv = 0.0f;
    {
        int trow = tid >> 2;
        int tcb = (tid & 3) * 16;
        u64 ez64 = hrow[trow] | hrow[trow + 1] | hrow[trow + 2] |
                   hrow[trow + 3] | hrow[trow + 4];
        u64 ezw = ez64 >> tcb;
        int q = (tcb + 4) >> 3;
        u32 ua = simg[trow + 4][q], ub = simg[trow + 4][q + 1], uc = simg[trow + 4][q + 2];
        u64 tb = ((u64)(ua >> 16)) | ((u64)ub << 16) | (((u64)(uc & 0xFFFFu)) << 48);
        const float4* pv4 = (const float4*)(pimg + (size_t)(r0 + trow) * W_IMG + (c0 + tcb));
#pragma unroll
        for (int kk = 0; kk < 4; ++kk) {
            float4 pv = pv4[kk];
            float ps[4] = {pv.x, pv.y, pv.z, pv.w};
#pragma unroll
            for (int cc = 0; cc < 4; ++cc) {
                int k = kk * 4 + cc;
                float p = ps[cc];
                float xx = ((tb >> (4 * k)) & 1) ? p : 1.0f - p;
                float lg = fmaxf(__logf(xx), -100.0f);
                float w = ((ezw >> k) & 1) ? 5.0f : 1.0f;
                accv = fmaf(w, -lg, accv);
            }
        }
    }

    for (int off = 32; off > 0; off >>= 1)
        accv += __shfl_down(accv, off);
    int wid = tid >> 6, lane = tid & 63;
    if (lane == 0) wsum[wid] = accv;
    __syncthreads();
    if (tid == 0) {
        int bi = (blockIdx.z * gridDim.y + blockIdx.y) * gridDim.x + blockIdx.x;
        partials[bi] = wsum[0] + wsum[1] + wsum[2] + wsum[3];
    }
}

__global__ __launch_bounds__(256)
void finalize_kernel(const float* __restrict__ partials, float* __restrict__ out,
                     int nblocks, double invN)
{
    __shared__ double ws[4];
    double s = 0.0;
    for (int i = threadIdx.x; i < nblocks; i += 256) s += (double)partials[i];
    for (int off = 32; off > 0; off >>= 1) s += __shfl_down(s, off);
    int wid = threadIdx.x >> 6, lane = threadIdx.x & 63;
    if (lane == 0) ws[wid] = s;
    __syncthreads();
    if (threadIdx.x == 0) out[0] = (float)((ws[0] + ws[1] + ws[2] + ws[3]) * invN);
}

extern "C" void kernel_launch(void* const* d_in, const int* in_sizes, int n_in,
                              void* d_out, int out_size, void* d_ws, size_t ws_size,
                              hipStream_t stream)
{
    (void)n_in; (void)out_size; (void)ws_size;
    const float* pred   = (const float*)d_in[0];
    const float* target = (const float*)d_in[1];
    const int N = in_sizes[0];
    const int B = N / (H_IMG * W_IMG);

    // ws layout: [0,16KB) per-block partials; [16KB, 16KB+2MB) packed target bits
    float* partials = (float*)d_ws;
    u32* packed = (u32*)((char*)d_ws + 16384);
    const int nwords = B * H_IMG * WPR;          // 524288 (2 MB)

    binarize_kernel<<<(nwords + 255) / 256, 256, 0, stream>>>(target, packed, nwords);

    dim3 grid(W_IMG / 64, H_IMG / 64, B);
    int nblocks = (W_IMG / 64) * (H_IMG / 64) * B;
    edge_loss_kernel<<<grid, NT, 0, stream>>>(pred, packed, partials);
    finalize_kernel<<<1, 256, 0, stream>>>(partials, (float*)d_out, nblocks,
                                           1.0 / (double)N);
}